// Round 1
// baseline (569.155 us; speedup 1.0000x reference)
//
#include <hip/hip_runtime.h>
#include <hip/hip_bf16.h>
#include <math.h>

// GAT forward: N=100000 nodes, E=1.6M edges (row sorted = dest), F_IN=128,
// F_OUT=32, HEADS=8, ALPHA=0.2. Output [N, 256] f32.
//
// Pipeline:
//  1) feat_gemm:  feat[N][256] = x @ W   (W = kernels reshaped [128][H*32])
//  2) a_proj:     a_s[N][8], a_n[N][8] = feat · att_self/att_neigh
//  3) row_ptr_k:  CSR offsets via binary search on sorted `row`
//  4) gat_scatter: per-node segmented softmax + SpMM + bias

#define F_IN   128
#define F_ALL  256   // HEADS * F_OUT
#define HEADS  8
#define F_OUT  32
#define ALPHA  0.2f

// ---------------- 1) feat = x @ W, 64x256 tile, 8x8 micro-tile ----------------
__global__ __launch_bounds__(256) void feat_gemm(const float* __restrict__ x,
                                                 const float* __restrict__ kern,
                                                 float* __restrict__ feat, int N) {
  __shared__ float As[32][64];    // [k][n]
  __shared__ float Bs[32][256];   // [k][c]
  const int t  = threadIdx.x;
  const int tx = t & 31, ty = t >> 5;
  const int n0 = blockIdx.x * 64;
  const int r0 = ty * 8, c0 = tx * 8;

  float acc[8][8];
#pragma unroll
  for (int i = 0; i < 8; i++)
#pragma unroll
    for (int j = 0; j < 8; j++) acc[i][j] = 0.f;

  const float4* kern4 = reinterpret_cast<const float4*>(kern);

  for (int kc = 0; kc < F_IN; kc += 32) {
    __syncthreads();
    // stage A: As[k][n] = x[n0+n][kc+k], 64 rows x 32 k
#pragma unroll
    for (int rep = 0; rep < 2; ++rep) {
      int v = t + rep * 256;            // 0..511
      int n = v >> 3, k4 = v & 7;
      int nn = n0 + n; if (nn >= N) nn = N - 1;
      float4 xv = *reinterpret_cast<const float4*>(&x[(size_t)nn * F_IN + kc + k4 * 4]);
      As[k4 * 4 + 0][n] = xv.x;
      As[k4 * 4 + 1][n] = xv.y;
      As[k4 * 4 + 2][n] = xv.z;
      As[k4 * 4 + 3][n] = xv.w;
    }
    // stage B: Bs[k][h*32+f] = kernels[h][kc+k][f]
#pragma unroll
    for (int rep = 0; rep < 8; ++rep) {
      int v = t + rep * 256;            // 0..2047
      int k = v >> 6, rem = v & 63;     // rem: float4 within the 256-col row
      int h = rem >> 3, f4 = rem & 7;
      float4 wv = kern4[((size_t)h * F_IN + kc + k) * 8 + f4];
      *reinterpret_cast<float4*>(&Bs[k][rem * 4]) = wv;
    }
    __syncthreads();
#pragma unroll
    for (int k = 0; k < 32; ++k) {
      float4 a0 = *reinterpret_cast<const float4*>(&As[k][r0]);
      float4 a1 = *reinterpret_cast<const float4*>(&As[k][r0 + 4]);
      float4 b0 = *reinterpret_cast<const float4*>(&Bs[k][c0]);
      float4 b1 = *reinterpret_cast<const float4*>(&Bs[k][c0 + 4]);
      float av[8] = {a0.x, a0.y, a0.z, a0.w, a1.x, a1.y, a1.z, a1.w};
      float bv[8] = {b0.x, b0.y, b0.z, b0.w, b1.x, b1.y, b1.z, b1.w};
#pragma unroll
      for (int i = 0; i < 8; i++)
#pragma unroll
        for (int j = 0; j < 8; j++) acc[i][j] = fmaf(av[i], bv[j], acc[i][j]);
    }
  }
#pragma unroll
  for (int i = 0; i < 8; i++) {
    int n = n0 + r0 + i;
    if (n < N) {
      float4 o0 = {acc[i][0], acc[i][1], acc[i][2], acc[i][3]};
      float4 o1 = {acc[i][4], acc[i][5], acc[i][6], acc[i][7]};
      *reinterpret_cast<float4*>(&feat[(size_t)n * F_ALL + c0])     = o0;
      *reinterpret_cast<float4*>(&feat[(size_t)n * F_ALL + c0 + 4]) = o1;
    }
  }
}

// ---------------- 2) attention logit projections ----------------
__global__ __launch_bounds__(256) void a_proj(const float* __restrict__ feat,
                                              const float* __restrict__ att_s,
                                              const float* __restrict__ att_n,
                                              float* __restrict__ a_s,
                                              float* __restrict__ a_n, int N) {
  int idx = blockIdx.x * 256 + threadIdx.x;
  if (idx >= N * HEADS) return;
  int n = idx >> 3, h = idx & 7;
  const float4* f4 = reinterpret_cast<const float4*>(&feat[(size_t)n * F_ALL + h * F_OUT]);
  const float4* s4 = reinterpret_cast<const float4*>(&att_s[h * F_OUT]);
  const float4* n4 = reinterpret_cast<const float4*>(&att_n[h * F_OUT]);
  float ss = 0.f, sn = 0.f;
#pragma unroll
  for (int i = 0; i < 8; i++) {
    float4 fv = f4[i], sv = s4[i], nv = n4[i];
    ss += fv.x * sv.x + fv.y * sv.y + fv.z * sv.z + fv.w * sv.w;
    sn += fv.x * nv.x + fv.y * nv.y + fv.z * nv.z + fv.w * nv.w;
  }
  a_s[idx] = ss;
  a_n[idx] = sn;
}

// ---------------- 3) CSR row offsets from sorted row[] ----------------
__global__ __launch_bounds__(256) void row_ptr_k(const int* __restrict__ row,
                                                 int* __restrict__ ptr, int N, int E) {
  int n = blockIdx.x * 256 + threadIdx.x;
  if (n > N) return;
  int lo = 0, hi = E;
  while (lo < hi) {
    int mid = (lo + hi) >> 1;
    if (row[mid] < n) lo = mid + 1; else hi = mid;
  }
  ptr[n] = lo;   // first edge with row >= n; ptr[N] = E
}

// ---------------- 4) per-node softmax + SpMM ----------------
__global__ __launch_bounds__(256) void gat_scatter(const float* __restrict__ feat,
                                                   const float* __restrict__ a_s,
                                                   const float* __restrict__ a_n,
                                                   const int* __restrict__ col,
                                                   const int* __restrict__ ptr,
                                                   const float* __restrict__ biases,
                                                   float* __restrict__ out, int N) {
  const int n = blockIdx.x;
  const int t = threadIdx.x;
  const int h = t >> 5;          // head group: 32 lanes (half-wave)
  const int f = t & 31;
  const int start = ptr[n], end = ptr[n + 1];
  const float as = a_s[n * HEADS + h];

  // pass 1: segment max (edge-parallel over 32 lanes)
  float mx = -INFINITY;
  for (int i = start + f; i < end; i += 32) {
    float ev = as + a_n[col[i] * HEADS + h];
    ev = ev > 0.f ? ev : ALPHA * ev;
    mx = fmaxf(mx, ev);
  }
#pragma unroll
  for (int m = 16; m; m >>= 1) mx = fmaxf(mx, __shfl_xor(mx, m));

  // pass 2: segment sum of exp
  float sm = 0.f;
  for (int i = start + f; i < end; i += 32) {
    float ev = as + a_n[col[i] * HEADS + h];
    ev = ev > 0.f ? ev : ALPHA * ev;
    sm += __expf(ev - mx);
  }
#pragma unroll
  for (int m = 16; m; m >>= 1) sm += __shfl_xor(sm, m);
  const float inv = (end > start) ? 1.0f / sm : 0.0f;

  // pass 3: weighted feature accumulation (serial over edges, lanes = feat dim)
  float acc = 0.f;
  for (int i = start; i < end; ++i) {
    int c = col[i];
    float ev = as + a_n[c * HEADS + h];
    ev = ev > 0.f ? ev : ALPHA * ev;
    float al = __expf(ev - mx) * inv;
    acc = fmaf(al, feat[(size_t)c * F_ALL + h * F_OUT + f], acc);
  }
  out[(size_t)n * F_ALL + t] = acc + biases[t];
}

extern "C" void kernel_launch(void* const* d_in, const int* in_sizes, int n_in,
                              void* d_out, int out_size, void* d_ws, size_t ws_size,
                              hipStream_t stream) {
  const float* x      = (const float*)d_in[0];
  const int*   row    = (const int*)d_in[1];
  const int*   col    = (const int*)d_in[2];
  const float* kern   = (const float*)d_in[3];
  const float* att_s  = (const float*)d_in[4];
  const float* att_n  = (const float*)d_in[5];
  const float* biases = (const float*)d_in[6];

  const int N = in_sizes[0] / F_IN;   // 100000
  const int E = in_sizes[1];          // 1600000

  // workspace layout (~110 MB): feat | a_s | a_n | row_ptr
  float* feat = (float*)d_ws;
  float* a_s  = feat + (size_t)N * F_ALL;
  float* a_n  = a_s + (size_t)N * HEADS;
  int*   ptr  = (int*)(a_n + (size_t)N * HEADS);
  float* out  = (float*)d_out;

  hipLaunchKernelGGL(feat_gemm, dim3((N + 63) / 64), dim3(256), 0, stream, x, kern, feat, N);
  hipLaunchKernelGGL(a_proj, dim3((N * HEADS + 255) / 256), dim3(256), 0, stream,
                     feat, att_s, att_n, a_s, a_n, N);
  hipLaunchKernelGGL(row_ptr_k, dim3((N + 1 + 255) / 256), dim3(256), 0, stream, row, ptr, N, E);
  hipLaunchKernelGGL(gat_scatter, dim3(N), dim3(256), 0, stream,
                     feat, a_s, a_n, col, ptr, biases, out, N);
}

// Round 2
// 316.501 us; speedup vs baseline: 1.7983x; 1.7983x over previous
//
#include <hip/hip_runtime.h>
#include <hip/hip_bf16.h>
#include <math.h>

// GAT forward: N=100000, E=1.6M (row sorted = dest), F_IN=128, F_OUT=32,
// HEADS=8, ALPHA=0.2. Output [N, 256] f32.
//
// Round 1 changes:
//  - feat stored bf16 (halves gather + write traffic; threshold allows it)
//  - a_s/a_n computed in GEMM epilogue (a_proj kernel removed)
//  - gat_scatter: edge weights computed ONCE per (edge,head) into LDS
//    (was ~34x redundant), unnormalized-exp accumulate + final 1/denom scale,
//    4-way unrolled independent accumulators for ILP.

#define F_IN   128
#define F_ALL  256   // HEADS * F_OUT
#define HEADS  8
#define F_OUT  32
#define ALPHA  0.2f
#define CHUNK  128   // edges cached in LDS per pass (deg ~ Poisson(16))

// ---------------- 1) feat = x @ W (bf16 out) + a_s/a_n epilogue ----------------
__global__ __launch_bounds__(256) void feat_gemm(const float* __restrict__ x,
                                                 const float* __restrict__ kern,
                                                 const float* __restrict__ att_s,
                                                 const float* __restrict__ att_n,
                                                 __hip_bfloat16* __restrict__ featb,
                                                 float* __restrict__ a_s,
                                                 float* __restrict__ a_n, int N) {
  __shared__ float As[32][64];    // [k][n]
  __shared__ float Bs[32][256];   // [k][c]
  const int t  = threadIdx.x;
  const int tx = t & 31, ty = t >> 5;
  const int n0 = blockIdx.x * 64;
  const int r0 = ty * 8, c0 = tx * 8;

  float acc[8][8];
#pragma unroll
  for (int i = 0; i < 8; i++)
#pragma unroll
    for (int j = 0; j < 8; j++) acc[i][j] = 0.f;

  const float4* kern4 = reinterpret_cast<const float4*>(kern);

  for (int kc = 0; kc < F_IN; kc += 32) {
    __syncthreads();
#pragma unroll
    for (int rep = 0; rep < 2; ++rep) {
      int v = t + rep * 256;            // 0..511
      int n = v >> 3, k4 = v & 7;
      int nn = n0 + n; if (nn >= N) nn = N - 1;
      float4 xv = *reinterpret_cast<const float4*>(&x[(size_t)nn * F_IN + kc + k4 * 4]);
      As[k4 * 4 + 0][n] = xv.x;
      As[k4 * 4 + 1][n] = xv.y;
      As[k4 * 4 + 2][n] = xv.z;
      As[k4 * 4 + 3][n] = xv.w;
    }
#pragma unroll
    for (int rep = 0; rep < 8; ++rep) {
      int v = t + rep * 256;            // 0..2047
      int k = v >> 6, rem = v & 63;
      int h = rem >> 3, f4 = rem & 7;
      float4 wv = kern4[((size_t)h * F_IN + kc + k) * 8 + f4];
      *reinterpret_cast<float4*>(&Bs[k][rem * 4]) = wv;
    }
    __syncthreads();
#pragma unroll
    for (int k = 0; k < 32; ++k) {
      float4 a0 = *reinterpret_cast<const float4*>(&As[k][r0]);
      float4 a1 = *reinterpret_cast<const float4*>(&As[k][r0 + 4]);
      float4 b0 = *reinterpret_cast<const float4*>(&Bs[k][c0]);
      float4 b1 = *reinterpret_cast<const float4*>(&Bs[k][c0 + 4]);
      float av[8] = {a0.x, a0.y, a0.z, a0.w, a1.x, a1.y, a1.z, a1.w};
      float bv[8] = {b0.x, b0.y, b0.z, b0.w, b1.x, b1.y, b1.z, b1.w};
#pragma unroll
      for (int i = 0; i < 8; i++)
#pragma unroll
        for (int j = 0; j < 8; j++) acc[i][j] = fmaf(av[i], bv[j], acc[i][j]);
    }
  }

  // epilogue: bf16 feat store + per-head a_s/a_n dot products
  const int h  = tx >> 2;           // head covered by this thread's 8 cols
  const int jb = (tx & 3) * 8;      // col offset within head
  float sv[8], nv[8];
#pragma unroll
  for (int j = 0; j < 8; j++) {
    sv[j] = att_s[h * F_OUT + jb + j];
    nv[j] = att_n[h * F_OUT + jb + j];
  }
#pragma unroll
  for (int i = 0; i < 8; i++) {
    int n = n0 + r0 + i;
    if (n < N) {
      alignas(16) __hip_bfloat16 hb[8];
#pragma unroll
      for (int j = 0; j < 8; j++) hb[j] = __float2bfloat16(acc[i][j]);
      *reinterpret_cast<float4*>(&featb[(size_t)n * F_ALL + c0]) =
          *reinterpret_cast<const float4*>(hb);
      float ps = 0.f, pn = 0.f;
#pragma unroll
      for (int j = 0; j < 8; j++) {
        ps = fmaf(acc[i][j], sv[j], ps);
        pn = fmaf(acc[i][j], nv[j], pn);
      }
      ps += __shfl_xor(ps, 1); ps += __shfl_xor(ps, 2);
      pn += __shfl_xor(pn, 1); pn += __shfl_xor(pn, 2);
      if ((tx & 3) == 0) {
        a_s[n * HEADS + h] = ps;
        a_n[n * HEADS + h] = pn;
      }
    }
  }
}

// ---------------- 2) CSR row offsets from sorted row[] ----------------
__global__ __launch_bounds__(256) void row_ptr_k(const int* __restrict__ row,
                                                 int* __restrict__ ptr, int N, int E) {
  int n = blockIdx.x * 256 + threadIdx.x;
  if (n > N) return;
  int lo = 0, hi = E;
  while (lo < hi) {
    int mid = (lo + hi) >> 1;
    if (row[mid] < n) lo = mid + 1; else hi = mid;
  }
  ptr[n] = lo;
}

// ---------------- 3) per-node softmax + SpMM ----------------
__global__ __launch_bounds__(256) void gat_scatter(const __hip_bfloat16* __restrict__ featb,
                                                   const float* __restrict__ a_s,
                                                   const float* __restrict__ a_n,
                                                   const int* __restrict__ col,
                                                   const int* __restrict__ ptr,
                                                   const float* __restrict__ biases,
                                                   float* __restrict__ out, int N) {
  __shared__ float wlds[HEADS][CHUNK + 1];  // per-head cached ev -> ex
  __shared__ int   clds[CHUNK];
  const int n = blockIdx.x;
  const int t = threadIdx.x;
  const int h = t >> 5;          // head group: 32 lanes
  const int f = t & 31;
  const int start = ptr[n], end = ptr[n + 1];
  const int deg = end - start;
  const float as = a_s[n * HEADS + h];

  // pass 1: leaky logits -> LDS (first CHUNK) + running max
  float mx = -INFINITY;
  for (int e = f; e < deg; e += 32) {
    int c = col[start + e];
    float ev = as + a_n[c * HEADS + h];
    ev = ev > 0.f ? ev : ALPHA * ev;
    mx = fmaxf(mx, ev);
    if (e < CHUNK) {
      wlds[h][e] = ev;
      if (h == 0) clds[e] = c;
    }
  }
#pragma unroll
  for (int m = 16; m; m >>= 1) mx = fmaxf(mx, __shfl_xor(mx, m));

  // pass 2: exp + sum (LDS now holds unnormalized ex for first CHUNK)
  float sm = 0.f;
  for (int e = f; e < deg; e += 32) {
    float ev;
    if (e < CHUNK) ev = wlds[h][e];
    else {
      int c = col[start + e];
      ev = as + a_n[c * HEADS + h];
      ev = ev > 0.f ? ev : ALPHA * ev;
    }
    float ex = __expf(ev - mx);
    sm += ex;
    if (e < CHUNK) wlds[h][e] = ex;
  }
#pragma unroll
  for (int m = 16; m; m >>= 1) sm += __shfl_xor(sm, m);
  const float inv = (deg > 0) ? 1.0f / sm : 0.0f;

  __syncthreads();  // clds (wave 0) + wlds visible to all waves

  // pass 3: acc = sum_e ex[e] * feat[col[e]] ; 4 independent accumulators
  float ac0 = 0.f, ac1 = 0.f, ac2 = 0.f, ac3 = 0.f;
  const int base = h * F_OUT + f;
  {
    const int cn = deg < CHUNK ? deg : CHUNK;
    int e = 0;
    for (; e + 4 <= cn; e += 4) {
      int ca = clds[e], cb = clds[e + 1], cc = clds[e + 2], cd = clds[e + 3];
      float wa = wlds[h][e],     wb = wlds[h][e + 1];
      float wc = wlds[h][e + 2], wd = wlds[h][e + 3];
      float fa = __bfloat162float(featb[(size_t)ca * F_ALL + base]);
      float fb = __bfloat162float(featb[(size_t)cb * F_ALL + base]);
      float fc = __bfloat162float(featb[(size_t)cc * F_ALL + base]);
      float fd = __bfloat162float(featb[(size_t)cd * F_ALL + base]);
      ac0 = fmaf(wa, fa, ac0);
      ac1 = fmaf(wb, fb, ac1);
      ac2 = fmaf(wc, fc, ac2);
      ac3 = fmaf(wd, fd, ac3);
    }
    for (; e < cn; ++e)
      ac0 = fmaf(wlds[h][e], __bfloat162float(featb[(size_t)clds[e] * F_ALL + base]), ac0);
  }

  // rare overflow chunks (deg > CHUNK)
  for (int cs = CHUNK; cs < deg; cs += CHUNK) {
    __syncthreads();
    int cn = deg - cs; if (cn > CHUNK) cn = CHUNK;
    for (int e = f; e < cn; e += 32) {
      int c = col[start + cs + e];
      if (h == 0) clds[e] = c;
      float ev = as + a_n[c * HEADS + h];
      ev = ev > 0.f ? ev : ALPHA * ev;
      wlds[h][e] = __expf(ev - mx);
    }
    __syncthreads();
    int e = 0;
    for (; e + 4 <= cn; e += 4) {
      int ca = clds[e], cb = clds[e + 1], cc = clds[e + 2], cd = clds[e + 3];
      float wa = wlds[h][e],     wb = wlds[h][e + 1];
      float wc = wlds[h][e + 2], wd = wlds[h][e + 3];
      ac0 = fmaf(wa, __bfloat162float(featb[(size_t)ca * F_ALL + base]), ac0);
      ac1 = fmaf(wb, __bfloat162float(featb[(size_t)cb * F_ALL + base]), ac1);
      ac2 = fmaf(wc, __bfloat162float(featb[(size_t)cc * F_ALL + base]), ac2);
      ac3 = fmaf(wd, __bfloat162float(featb[(size_t)cd * F_ALL + base]), ac3);
    }
    for (; e < cn; ++e)
      ac0 = fmaf(wlds[h][e], __bfloat162float(featb[(size_t)clds[e] * F_ALL + base]), ac0);
  }

  out[(size_t)n * F_ALL + t] = (ac0 + ac1 + ac2 + ac3) * inv + biases[t];
}

extern "C" void kernel_launch(void* const* d_in, const int* in_sizes, int n_in,
                              void* d_out, int out_size, void* d_ws, size_t ws_size,
                              hipStream_t stream) {
  const float* x      = (const float*)d_in[0];
  const int*   row    = (const int*)d_in[1];
  const int*   col    = (const int*)d_in[2];
  const float* kern   = (const float*)d_in[3];
  const float* att_s  = (const float*)d_in[4];
  const float* att_n  = (const float*)d_in[5];
  const float* biases = (const float*)d_in[6];

  const int N = in_sizes[0] / F_IN;   // 100000
  const int E = in_sizes[1];          // 1600000

  // workspace: featb (bf16) | a_s | a_n | row_ptr   (~58 MB)
  __hip_bfloat16* featb = (__hip_bfloat16*)d_ws;
  float* a_s = (float*)(featb + (size_t)N * F_ALL);
  float* a_n = a_s + (size_t)N * HEADS;
  int*   ptr = (int*)(a_n + (size_t)N * HEADS);
  float* out = (float*)d_out;

  hipLaunchKernelGGL(feat_gemm, dim3((N + 63) / 64), dim3(256), 0, stream,
                     x, kern, att_s, att_n, featb, a_s, a_n, N);
  hipLaunchKernelGGL(row_ptr_k, dim3((N + 1 + 255) / 256), dim3(256), 0, stream, row, ptr, N, E);
  hipLaunchKernelGGL(gat_scatter, dim3(N), dim3(256), 0, stream,
                     featb, a_s, a_n, col, ptr, biases, out, N);
}